// Round 4
// baseline (179.113 us; speedup 1.0000x reference)
//
#include <hip/hip_runtime.h>
#include <hip/hip_bf16.h>

#define BSZ 2
#define SEQ 2048
#define DIN 1024
#define EMB 1024
#define NH  16
#define HD  64
#define QKV3 3072

typedef short bf16x8 __attribute__((ext_vector_type(8)));
typedef float f32x4  __attribute__((ext_vector_type(4)));
typedef unsigned int u32;

#define CSCL 0.18033688f   // 0.125 * log2(e)

__device__ __forceinline__ unsigned short f2bf(float f) {
    union { float f; unsigned int u; } v; v.f = f;
    unsigned int r = v.u + 0x7fffu + ((v.u >> 16) & 1u);   // RNE
    return (unsigned short)(r >> 16);
}

__device__ __forceinline__ unsigned cvt_pk_bf16(float lo, float hi) {
    unsigned r;
    asm("v_cvt_pk_bf16_f32 %0, %1, %2" : "=v"(r) : "v"(lo), "v"(hi));
    return r;
}

// async global -> LDS, 16 B per lane; lds base must be wave-uniform
__device__ __forceinline__ void gload16(const unsigned short* g, short* lds) {
    __builtin_amdgcn_global_load_lds(
        (const __attribute__((address_space(1))) u32*)g,
        (__attribute__((address_space(3))) u32*)lds, 16, 0, 0);
}

// ---------------------------------------------------------------------------
// fp32 -> bf16 conversion (8 elems/thread)
// ---------------------------------------------------------------------------
__global__ __launch_bounds__(256) void f2bf_kernel(
    const float* __restrict__ in, unsigned short* __restrict__ out, int n)
{
    int i = (blockIdx.x * 256 + threadIdx.x) * 8;
    if (i >= n) return;
    float4 a = *(const float4*)(in + i);
    float4 b = *(const float4*)(in + i + 4);
    bf16x8 r;
    r[0] = (short)f2bf(a.x); r[1] = (short)f2bf(a.y);
    r[2] = (short)f2bf(a.z); r[3] = (short)f2bf(a.w);
    r[4] = (short)f2bf(b.x); r[5] = (short)f2bf(b.y);
    r[6] = (short)f2bf(b.z); r[7] = (short)f2bf(b.w);
    *(bf16x8*)(out + i) = r;
}

// W_qkv conversion with Q-row pre-scale by CSCL (rows with (n%192)<64)
__global__ __launch_bounds__(256) void f2bf_wqkv(
    const float* __restrict__ in, unsigned short* __restrict__ out)
{
    int i = (blockIdx.x * 256 + threadIdx.x) * 8;
    int row = i >> 10;                       // DIN = 1024
    float sc = ((row % 192) < 64) ? CSCL : 1.0f;
    float4 a = *(const float4*)(in + i);
    float4 b = *(const float4*)(in + i + 4);
    bf16x8 r;
    r[0] = (short)f2bf(a.x * sc); r[1] = (short)f2bf(a.y * sc);
    r[2] = (short)f2bf(a.z * sc); r[3] = (short)f2bf(a.w * sc);
    r[4] = (short)f2bf(b.x * sc); r[5] = (short)f2bf(b.y * sc);
    r[6] = (short)f2bf(b.z * sc); r[7] = (short)f2bf(b.w * sc);
    *(bf16x8*)(out + i) = r;
}

// scaled fp32 copy of b_qkv (Q entries * CSCL)
__global__ void scale_bias(const float* __restrict__ b, float* __restrict__ o)
{
    int i = blockIdx.x * 256 + threadIdx.x;   // 3072
    float v = b[i];
    if ((i % 192) < 64) v *= CSCL;
    o[i] = v;
}

// ---------------------------------------------------------------------------
// bf16 MFMA GEMM (NT): C = A @ W^T + bias. 128x128 tile, BK=32, 4 waves.
// global_load_lds staging into linear [128][32] LDS (m97 structure).
// MODE: 0 = f32 out; 1 = bf16 out; 2 = bf16 out + K-section chunk swizzle
// (stored[row][c^(row&7)] = K[row][c]) so attn can global_load_lds linearly.
// ---------------------------------------------------------------------------
template <int MODE>
__global__ __launch_bounds__(256) void gemm_bf16_nt(
    const unsigned short* __restrict__ A, const unsigned short* __restrict__ W,
    const float* __restrict__ bias, void* __restrict__ Cout,
    int M, int N, int K)
{
    __shared__ short As[128 * 32];
    __shared__ short Bs[128 * 32];

    const int tid = threadIdx.x;
    // bijective XCD swizzle over linearized grid (nwg % 8 == 0)
    const int nwg = gridDim.x * gridDim.y;
    int lin = blockIdx.y * gridDim.x + blockIdx.x;
    lin = (lin & 7) * (nwg >> 3) + (lin >> 3);
    const int bx = lin % gridDim.x, by = lin / gridDim.x;

    const int m0 = by * 128, n0 = bx * 128;
    const int w = tid >> 6, lane = tid & 63;
    const int lg = lane >> 4, l15 = lane & 15;
    const int wr = w >> 1, wc = w & 1;

    const int srow = w * 16 + (lane >> 2);      // staging row (issue adds 64)
    const int scol = (lane & 3) * 8;            // staging col (shorts)
    const unsigned short* Ap = A + (size_t)(m0 + srow) * K + scol;
    const unsigned short* Wp = W + (size_t)(n0 + srow) * K + scol;
    short* AsW = As + w * 512;                  // wave-uniform LDS base
    short* BsW = Bs + w * 512;

    f32x4 acc[4][4] = {};

    for (int k0 = 0; k0 < K; k0 += 32) {
        gload16(Ap + k0,                  AsW);
        gload16(Ap + k0 + (size_t)64 * K, AsW + 2048);
        gload16(Wp + k0,                  BsW);
        gload16(Wp + k0 + (size_t)64 * K, BsW + 2048);
        __syncthreads();

        bf16x8 af[4], bfr[4];
        #pragma unroll
        for (int mf = 0; mf < 4; ++mf)
            af[mf] = *(const bf16x8*)&As[(wr * 64 + mf * 16 + l15) * 32 + lg * 8];
        #pragma unroll
        for (int nf = 0; nf < 4; ++nf)
            bfr[nf] = *(const bf16x8*)&Bs[(wc * 64 + nf * 16 + l15) * 32 + lg * 8];
        #pragma unroll
        for (int mf = 0; mf < 4; ++mf)
            #pragma unroll
            for (int nf = 0; nf < 4; ++nf)
                acc[mf][nf] = __builtin_amdgcn_mfma_f32_16x16x32_bf16(
                    af[mf], bfr[nf], acc[mf][nf], 0, 0, 0);
        __syncthreads();
    }

    #pragma unroll
    for (int nf = 0; nf < 4; ++nf) {
        int colbase = n0 + wc * 64 + nf * 16;
        bool isK = (MODE == 2) && (((colbase >> 6) % 3) == 1);
        int col = colbase + l15;
        float bv = bias[col];
        #pragma unroll
        for (int mf = 0; mf < 4; ++mf) {
            #pragma unroll
            for (int r = 0; r < 4; ++r) {
                int row = m0 + wr * 64 + mf * 16 + lg * 4 + r;
                float v = acc[mf][nf][r] + bv;
                if (MODE == 0) {
                    ((float*)Cout)[(size_t)row * N + col] = v;
                } else {
                    int scol2 = col;
                    if (isK) {
                        int cc = (col >> 3) & 7;
                        scol2 = col + (((cc ^ (row & 7)) - cc) << 3);
                    }
                    ((unsigned short*)Cout)[(size_t)row * N + scol2] = f2bf(v);
                }
            }
        }
    }
}

// ---------------------------------------------------------------------------
// V pre-transpose: vtg[b][h][d][s], chunk-swizzled within each 128-key tile
// (stored[d][tile][c^(d&15)] = V^T[d][tile][c]) for linear global_load_lds.
// ---------------------------------------------------------------------------
__global__ __launch_bounds__(256) void vtranspose(
    const unsigned short* __restrict__ qkvb, unsigned short* __restrict__ vtg)
{
    const int tid = threadIdx.x;
    const int st = blockIdx.x, h = blockIdx.y, bz = blockIdx.z;
    const int colv = h * 192 + 128;

    #pragma unroll
    for (int i = 0; i < 2; ++i) {
        int id = tid + i * 256;          // 0..511
        int d = id >> 3, sc = id & 7;    // 64 d x 8 s-chunks (of this 64-tile)
        bf16x8 v;
        #pragma unroll
        for (int jj = 0; jj < 8; ++jj)
            v[jj] = (short)qkvb[(size_t)(bz * SEQ + st * 64 + sc * 8 + jj) * QKV3 + colv + d];
        int g = st * 8 + sc;                           // global 8-key chunk idx
        int gs = (g & ~15) | ((g & 15) ^ (d & 15));    // swizzle within 128-tile
        *(bf16x8*)&vtg[((size_t)(bz * NH + h) * HD + d) * SEQ + gs * 8] = v;
    }
}

// ---------------------------------------------------------------------------
// MFMA flash attention: swapped QK^T, in-register softmax (pre-scaled scores),
// defer-max, cvt_pk P-packing, global_load_lds staging of K and V^T.
// grid 1024 (XCD-swizzled), 256 thr (4 waves x 16 q-rows), KVBLK=128.
// ---------------------------------------------------------------------------
__global__ __launch_bounds__(256, 4) void attn_mfma(
    const unsigned short* __restrict__ qkvb,
    const unsigned short* __restrict__ vtg,
    unsigned short* __restrict__ attnb)
{
    __shared__ short Ks[128 * 64];     // [key][c], rows hold pre-swizzled chunks
    __shared__ short VT[64 * 128];     // [d][c], rows hold pre-swizzled chunks

    const int tid = threadIdx.x;
    const int fl = blockIdx.x;
    const int swz = ((fl & 7) << 7) | (fl >> 3);
    const int qt = swz & 31, h = (swz >> 5) & 15, b = swz >> 9;

    const int w = tid >> 6, lane = tid & 63;
    const int lg = lane >> 4, l15 = lane & 15;

    const int row0 = b * SEQ + qt * 64;
    const int colq = h * 192, colk = colq + 64;

    // Q fragments (pre-scaled by CSCL at the QKV GEMM)
    bf16x8 qa[2];
    {
        const unsigned short* qp =
            qkvb + (size_t)(row0 + w * 16 + l15) * QKV3 + colq + lg * 8;
        qa[0] = *(const bf16x8*)qp;
        qa[1] = *(const bf16x8*)(qp + 32);
    }

    // staging source bases (per-lane global, wave-uniform LDS)
    const unsigned short* kg = qkvb + (size_t)(b * SEQ + w * 8 + (lane >> 3)) * QKV3
                                    + colk + (lane & 7) * 8;
    const unsigned short* vg = vtg + ((size_t)(b * NH + h) * HD + w * 4 + (lane >> 4)) * SEQ
                                   + (lane & 15) * 8;
    short* KsW = Ks + w * 512;
    short* VtW = VT + w * 512;

    float m_run = -INFINITY, l_run = 0.0f;
    f32x4 o[4] = {};

    for (int kt = 0; kt < SEQ / 128; ++kt) {
        // ---- stage K [128][64] and V^T [64][128] via global_load_lds ----
        const unsigned short* kg0 = kg + (size_t)(kt * 128) * QKV3;
        const unsigned short* vg0 = vg + kt * 128;
        #pragma unroll
        for (int i = 0; i < 4; ++i)
            gload16(kg0 + (size_t)(i * 32) * QKV3, KsW + i * 2048);
        #pragma unroll
        for (int i = 0; i < 4; ++i)
            gload16(vg0 + (size_t)(i * 16) * SEQ, VtW + i * 2048);
        __syncthreads();

        // ---- S^T = mfma(K, Q): lane holds S^T[key=kf*16+lg*4+r][q=l15] ----
        f32x4 s[8];
        #pragma unroll
        for (int kf = 0; kf < 8; ++kf) s[kf] = (f32x4){0.f, 0.f, 0.f, 0.f};
        #pragma unroll
        for (int kc = 0; kc < 2; ++kc) {
            #pragma unroll
            for (int kf = 0; kf < 8; ++kf) {
                int key = kf * 16 + l15;
                int ch = (kc * 4 + lg) ^ (key & 7);
                bf16x8 kfr = *(const bf16x8*)&Ks[key * 64 + (ch << 3)];
                s[kf] = __builtin_amdgcn_mfma_f32_16x16x32_bf16(kfr, qa[kc], s[kf], 0, 0, 0);
            }
        }

        // ---- online softmax, scores already in exp2 domain ----
        float mx = -INFINITY;
        #pragma unroll
        for (int kf = 0; kf < 8; ++kf)
            mx = fmaxf(mx, fmaxf(fmaxf(s[kf][0], s[kf][1]), fmaxf(s[kf][2], s[kf][3])));
        mx = fmaxf(mx, __shfl_xor(mx, 16));
        mx = fmaxf(mx, __shfl_xor(mx, 32));

        if (!__all(mx <= m_run + 12.0f)) {     // defer-max (T13), wave-uniform
            float mnew = fmaxf(m_run, mx);
            float alpha = exp2f(m_run - mnew);
            m_run = mnew;
            l_run *= alpha;
            #pragma unroll
            for (int r = 0; r < 4; ++r) {
                float ar = __shfl(alpha, lg * 20 + r);
                #pragma unroll
                for (int nf = 0; nf < 4; ++nf) o[nf][r] *= ar;
            }
        }

        float sum = 0.0f;
        unsigned pk[8][2];
        #pragma unroll
        for (int kf = 0; kf < 8; ++kf) {
            float p0 = exp2f(s[kf][0] - m_run);
            float p1 = exp2f(s[kf][1] - m_run);
            float p2 = exp2f(s[kf][2] - m_run);
            float p3 = exp2f(s[kf][3] - m_run);
            sum += (p0 + p1) + (p2 + p3);
            pk[kf][0] = cvt_pk_bf16(p0, p1);
            pk[kf][1] = cvt_pk_bf16(p2, p3);
        }
        sum += __shfl_xor(sum, 16);
        sum += __shfl_xor(sum, 32);
        l_run += sum;

        // ---- PV: redistribute P to A-frag nominal (row=q=l15, k=key) ----
        const int srcA = ((lg & 1) << 5) | l15;
        const int srcB = srcA + 16;
        const bool hi = (lg >= 2);
        #pragma unroll
        for (int kc = 0; kc < 4; ++kc) {
            unsigned a0 = (unsigned)__shfl((int)pk[2 * kc][0], srcA);
            unsigned a1 = (unsigned)__shfl((int)pk[2 * kc][1], srcA);
            unsigned a2 = (unsigned)__shfl((int)pk[2 * kc][0], srcB);
            unsigned a3 = (unsigned)__shfl((int)pk[2 * kc][1], srcB);
            unsigned c0 = (unsigned)__shfl((int)pk[2 * kc + 1][0], srcA);
            unsigned c1 = (unsigned)__shfl((int)pk[2 * kc + 1][1], srcA);
            unsigned c2 = (unsigned)__shfl((int)pk[2 * kc + 1][0], srcB);
            unsigned c3 = (unsigned)__shfl((int)pk[2 * kc + 1][1], srcB);
            union { unsigned u[4]; bf16x8 v; } pa;
            pa.u[0] = hi ? c0 : a0;
            pa.u[1] = hi ? c1 : a1;
            pa.u[2] = hi ? c2 : a2;
            pa.u[3] = hi ? c3 : a3;
            #pragma unroll
            for (int nf = 0; nf < 4; ++nf) {
                int d = nf * 16 + l15;
                int ch = (kc * 4 + lg) ^ (d & 15);
                bf16x8 vb = *(const bf16x8*)&VT[d * 128 + (ch << 3)];
                o[nf] = __builtin_amdgcn_mfma_f32_16x16x32_bf16(pa.v, vb, o[nf], 0, 0, 0);
            }
        }
        __syncthreads();
    }

    // ---- epilogue ----
    #pragma unroll
    for (int r = 0; r < 4; ++r) {
        float lr = __shfl(l_run, lg * 20 + r);
        float inv = 1.0f / lr;
        int qrow = w * 16 + lg * 4 + r;
        #pragma unroll
        for (int nf = 0; nf < 4; ++nf)
            attnb[(size_t)(row0 + qrow) * EMB + h * HD + nf * 16 + l15] =
                f2bf(o[nf][r] * inv);
    }
}

// ---------------------------------------------------------------------------
extern "C" void kernel_launch(void* const* d_in, const int* in_sizes, int n_in,
                              void* d_out, int out_size, void* d_ws, size_t ws_size,
                              hipStream_t stream) {
    const float* x     = (const float*)d_in[0];
    const float* W_qkv = (const float*)d_in[1];
    const float* b_qkv = (const float*)d_in[2];
    const float* W_out = (const float*)d_in[3];
    const float* b_out = (const float*)d_in[4];
    float* out = (float*)d_out;

    // ws: xb 8M | wqkvb 6M | woutb 2M | qkvb 24M | attnb 8M | vtg 8M | bqs 12K
    char* ws = (char*)d_ws;
    unsigned short* xb     = (unsigned short*)(ws);
    unsigned short* wqkvb  = (unsigned short*)(ws + (8u << 20));
    unsigned short* woutb  = (unsigned short*)(ws + (14u << 20));
    unsigned short* qkvb   = (unsigned short*)(ws + (16u << 20));
    unsigned short* attnb  = (unsigned short*)(ws + (40u << 20));
    unsigned short* vtg    = (unsigned short*)(ws + (48u << 20));
    float*          bqs    = (float*)(ws + (56u << 20));

    const int M = BSZ * SEQ;            // 4096
    const int nx = M * DIN;
    const int nwq = QKV3 * DIN;
    const int nwo = EMB * EMB;

    f2bf_kernel<<<nx  / (8 * 256), 256, 0, stream>>>(x,     xb,    nx);
    f2bf_wqkv  <<<nwq / (8 * 256), 256, 0, stream>>>(W_qkv, wqkvb);
    f2bf_kernel<<<nwo / (8 * 256), 256, 0, stream>>>(W_out, woutb, nwo);
    scale_bias <<<QKV3 / 256, 256, 0, stream>>>(b_qkv, bqs);

    gemm_bf16_nt<2><<<dim3(QKV3 / 128, M / 128), 256, 0, stream>>>(
        xb, wqkvb, bqs, qkvb, M, QKV3, DIN);

    vtranspose<<<dim3(SEQ / 64, NH, BSZ), 256, 0, stream>>>(qkvb, vtg);

    attn_mfma<<<1024, 256, 0, stream>>>(qkvb, vtg, attnb);

    gemm_bf16_nt<0><<<dim3(EMB / 128, M / 128), 256, 0, stream>>>(
        attnb, woutb, b_out, out, M, EMB, DIN);
}

// Round 5
// 153.813 us; speedup vs baseline: 1.1645x; 1.1645x over previous
//
#include <hip/hip_runtime.h>
#include <hip/hip_bf16.h>

#define BSZ 2
#define SEQ 2048
#define DIN 1024
#define EMB 1024
#define NH  16
#define HD  64
#define QKV3 3072

typedef short bf16x8 __attribute__((ext_vector_type(8)));
typedef short bf16x4 __attribute__((ext_vector_type(4)));
typedef float f32x4  __attribute__((ext_vector_type(4)));
typedef unsigned int u32;

#define CSCL 0.18033688f   // 0.125 * log2(e)

__device__ __forceinline__ unsigned short f2bf(float f) {
    union { float f; unsigned int u; } v; v.f = f;
    unsigned int r = v.u + 0x7fffu + ((v.u >> 16) & 1u);   // RNE
    return (unsigned short)(r >> 16);
}

__device__ __forceinline__ unsigned cvt_pk_bf16(float lo, float hi) {
    unsigned r;
    asm("v_cvt_pk_bf16_f32 %0, %1, %2" : "=v"(r) : "v"(lo), "v"(hi));
    return r;
}

// async global -> LDS, 16 B per lane; lds base must be wave-uniform
__device__ __forceinline__ void gload16(const unsigned short* g, short* lds) {
    __builtin_amdgcn_global_load_lds(
        (const __attribute__((address_space(1))) u32*)g,
        (__attribute__((address_space(3))) u32*)lds, 16, 0, 0);
}

// ---------------------------------------------------------------------------
// Fused fp32->bf16 conversion: x | W_qkv (Q-rows pre-scaled) | W_out | b_qkv
// ---------------------------------------------------------------------------
#define NX  (BSZ * SEQ * DIN)     // 4194304
#define NWQ (QKV3 * DIN)          // 3145728
#define NWO (EMB * EMB)           // 1048576
#define NTOT (NX + NWQ + NWO + QKV3)

__global__ __launch_bounds__(256) void convert_all(
    const float* __restrict__ x, const float* __restrict__ Wq,
    const float* __restrict__ Wo, const float* __restrict__ bq,
    unsigned short* __restrict__ xb, unsigned short* __restrict__ wqb,
    unsigned short* __restrict__ wob, float* __restrict__ bqs)
{
    int i8 = (blockIdx.x * 256 + threadIdx.x) * 8;
    if (i8 >= NTOT) return;
    if (i8 < NX) {
        float4 a = *(const float4*)(x + i8);
        float4 b = *(const float4*)(x + i8 + 4);
        bf16x8 r;
        r[0] = (short)f2bf(a.x); r[1] = (short)f2bf(a.y);
        r[2] = (short)f2bf(a.z); r[3] = (short)f2bf(a.w);
        r[4] = (short)f2bf(b.x); r[5] = (short)f2bf(b.y);
        r[6] = (short)f2bf(b.z); r[7] = (short)f2bf(b.w);
        *(bf16x8*)(xb + i8) = r;
    } else if (i8 < NX + NWQ) {
        int i = i8 - NX;
        int row = i >> 10;
        float sc = ((row % 192) < 64) ? CSCL : 1.0f;
        float4 a = *(const float4*)(Wq + i);
        float4 b = *(const float4*)(Wq + i + 4);
        bf16x8 r;
        r[0] = (short)f2bf(a.x * sc); r[1] = (short)f2bf(a.y * sc);
        r[2] = (short)f2bf(a.z * sc); r[3] = (short)f2bf(a.w * sc);
        r[4] = (short)f2bf(b.x * sc); r[5] = (short)f2bf(b.y * sc);
        r[6] = (short)f2bf(b.z * sc); r[7] = (short)f2bf(b.w * sc);
        *(bf16x8*)(wqb + i) = r;
    } else if (i8 < NX + NWQ + NWO) {
        int i = i8 - NX - NWQ;
        float4 a = *(const float4*)(Wo + i);
        float4 b = *(const float4*)(Wo + i + 4);
        bf16x8 r;
        r[0] = (short)f2bf(a.x); r[1] = (short)f2bf(a.y);
        r[2] = (short)f2bf(a.z); r[3] = (short)f2bf(a.w);
        r[4] = (short)f2bf(b.x); r[5] = (short)f2bf(b.y);
        r[6] = (short)f2bf(b.z); r[7] = (short)f2bf(b.w);
        *(bf16x8*)(wob + i) = r;
    } else {
        int i = i8 - NX - NWQ - NWO;
        #pragma unroll
        for (int j = 0; j < 8; ++j) {
            float v = bq[i + j];
            if (((i + j) % 192) < 64) v *= CSCL;
            bqs[i + j] = v;
        }
    }
}

// ---------------------------------------------------------------------------
// bf16 MFMA GEMM (NT): C = A @ W^T + bias. 128x128 tile, BK=32, 4 waves.
// global_load_lds staging into linear [128][32] LDS (m97 structure).
// MODE 0: f32 out.  MODE 2: qkv epilogue — Q cols normal bf16, K cols
// chunk-swizzled bf16 (stored[row][c^(row&7)]), V cols written transposed +
// chunk-swizzled into vtg[b][h][d][s] (b64-packed), qkvb V-section skipped.
// ---------------------------------------------------------------------------
template <int MODE>
__global__ __launch_bounds__(256) void gemm_bf16_nt(
    const unsigned short* __restrict__ A, const unsigned short* __restrict__ W,
    const float* __restrict__ bias, void* __restrict__ Cout,
    unsigned short* __restrict__ Vout,
    int M, int N, int K)
{
    __shared__ short As[128 * 32];
    __shared__ short Bs[128 * 32];

    const int tid = threadIdx.x;
    const int m0 = blockIdx.y * 128, n0 = blockIdx.x * 128;
    const int w = tid >> 6, lane = tid & 63;
    const int lg = lane >> 4, l15 = lane & 15;
    const int wr = w >> 1, wc = w & 1;

    const int srow = w * 16 + (lane >> 2);
    const int scol = (lane & 3) * 8;
    const unsigned short* Ap = A + (size_t)(m0 + srow) * K + scol;
    const unsigned short* Wp = W + (size_t)(n0 + srow) * K + scol;
    short* AsW = As + w * 512;
    short* BsW = Bs + w * 512;

    f32x4 acc[4][4] = {};

    for (int k0 = 0; k0 < K; k0 += 32) {
        gload16(Ap + k0,                  AsW);
        gload16(Ap + k0 + (size_t)64 * K, AsW + 2048);
        gload16(Wp + k0,                  BsW);
        gload16(Wp + k0 + (size_t)64 * K, BsW + 2048);
        __syncthreads();

        bf16x8 af[4], bfr[4];
        #pragma unroll
        for (int mf = 0; mf < 4; ++mf)
            af[mf] = *(const bf16x8*)&As[(wr * 64 + mf * 16 + l15) * 32 + lg * 8];
        #pragma unroll
        for (int nf = 0; nf < 4; ++nf)
            bfr[nf] = *(const bf16x8*)&Bs[(wc * 64 + nf * 16 + l15) * 32 + lg * 8];
        #pragma unroll
        for (int mf = 0; mf < 4; ++mf)
            #pragma unroll
            for (int nf = 0; nf < 4; ++nf)
                acc[mf][nf] = __builtin_amdgcn_mfma_f32_16x16x32_bf16(
                    af[mf], bfr[nf], acc[mf][nf], 0, 0, 0);
        __syncthreads();
    }

    #pragma unroll
    for (int nf = 0; nf < 4; ++nf) {
        int colbase = n0 + wc * 64 + nf * 16;
        int col = colbase + l15;
        float bv = bias[col];
        int sect = (MODE == 2) ? ((colbase % 192) / 64) : 0;
        if (MODE == 2 && sect == 2) {
            // ---- V: write transposed + swizzled into vtg ----
            int h = colbase / 192;
            int dd = (colbase % 192) - 128 + l15;    // 0..63
            #pragma unroll
            for (int mf = 0; mf < 4; ++mf) {
                int row = m0 + wr * 64 + mf * 16 + lg * 4;   // r = 0
                int bz = row >> 11, sl = row & 2047;
                int cp = ((sl >> 3) & 15) ^ (dd & 15);
                int sdst = (sl & ~127) | (cp << 3) | (sl & 7);
                bf16x4 p;
                #pragma unroll
                for (int r = 0; r < 4; ++r)
                    p[r] = (short)f2bf(acc[mf][nf][r] + bv);
                *(bf16x4*)&Vout[((size_t)(bz * NH + h) * HD + dd) * SEQ + sdst] = p;
            }
        } else {
            bool isK = (MODE == 2) && (sect == 1);
            #pragma unroll
            for (int mf = 0; mf < 4; ++mf) {
                #pragma unroll
                for (int r = 0; r < 4; ++r) {
                    int row = m0 + wr * 64 + mf * 16 + lg * 4 + r;
                    float v = acc[mf][nf][r] + bv;
                    if (MODE == 0) {
                        ((float*)Cout)[(size_t)row * N + col] = v;
                    } else {
                        int scol2 = col;
                        if (isK) {
                            int cc = (col >> 3) & 7;
                            scol2 = col + (((cc ^ (row & 7)) - cc) << 3);
                        }
                        ((unsigned short*)Cout)[(size_t)row * N + scol2] = f2bf(v);
                    }
                }
            }
        }
    }
}

// ---------------------------------------------------------------------------
// MFMA flash attention: Q-tile 128 (4 waves x 32 q-rows), KVBLK=128,
// double-buffered K/V LDS with stage-ahead global_load_lds prefetch,
// swapped QK^T + in-register softmax (pre-scaled), defer-max, cvt_pk.
// grid 512 (XCD-swizzled), 256 thr.
// ---------------------------------------------------------------------------
__global__ __launch_bounds__(256, 2) void attn_mfma(
    const unsigned short* __restrict__ qkvb,
    const unsigned short* __restrict__ vtg,
    unsigned short* __restrict__ attnb)
{
    __shared__ short Ks[2 * 128 * 64];   // [buf][key][c], pre-swizzled chunks
    __shared__ short VT[2 * 64 * 128];   // [buf][d][c],   pre-swizzled chunks

    const int tid = threadIdx.x;
    const int fl = blockIdx.x;
    const int swz = ((fl & 7) << 6) | (fl >> 3);   // bijective, 512 blocks
    const int qt = swz & 15, h = (swz >> 4) & 15, b = swz >> 8;

    const int w = tid >> 6, lane = tid & 63;
    const int lg = lane >> 4, l15 = lane & 15;

    const int row0 = b * SEQ + qt * 128;
    const int colq = h * 192, colk = colq + 64;

    // Q fragments: qa[mq][kc], q-row = row0 + w*32 + mq*16 + l15 (CSCL-scaled)
    bf16x8 qa[2][2];
    #pragma unroll
    for (int mq = 0; mq < 2; ++mq) {
        const unsigned short* qp =
            qkvb + (size_t)(row0 + w * 32 + mq * 16 + l15) * QKV3 + colq + lg * 8;
        qa[mq][0] = *(const bf16x8*)qp;
        qa[mq][1] = *(const bf16x8*)(qp + 32);
    }

    // staging bases (per-lane global, wave-uniform LDS)
    const unsigned short* kg = qkvb + (size_t)(b * SEQ + w * 8 + (lane >> 3)) * QKV3
                                    + colk + (lane & 7) * 8;
    const unsigned short* vg = vtg + ((size_t)(b * NH + h) * HD + w * 4 + (lane >> 4)) * SEQ
                                   + (lane & 15) * 8;

    float m_run[2] = {-INFINITY, -INFINITY};
    float l_run[2] = {0.0f, 0.0f};
    f32x4 o[2][4] = {};

    const int NT = SEQ / 128;   // 16

    // prologue: stage tile 0 into buf 0
    {
        short* KsW = Ks + w * 512;
        short* VtW = VT + w * 512;
        #pragma unroll
        for (int i = 0; i < 4; ++i)
            gload16(kg + (size_t)(i * 32) * QKV3, KsW + i * 2048);
        #pragma unroll
        for (int i = 0; i < 4; ++i)
            gload16(vg + (size_t)(i * 16) * SEQ, VtW + i * 2048);
    }
    __syncthreads();

    for (int kt = 0; kt < NT; ++kt) {
        const int cur = kt & 1;
        short* KsC = Ks + cur * 8192;
        short* VtC = VT + cur * 8192;

        // ---- stage-ahead: issue next tile's loads into buf^1 ----
        if (kt < NT - 1) {
            short* KsW = Ks + (cur ^ 1) * 8192 + w * 512;
            short* VtW = VT + (cur ^ 1) * 8192 + w * 512;
            const unsigned short* kg0 = kg + (size_t)((kt + 1) * 128) * QKV3;
            const unsigned short* vg0 = vg + (kt + 1) * 128;
            #pragma unroll
            for (int i = 0; i < 4; ++i)
                gload16(kg0 + (size_t)(i * 32) * QKV3, KsW + i * 2048);
            #pragma unroll
            for (int i = 0; i < 4; ++i)
                gload16(vg0 + (size_t)(i * 16) * SEQ, VtW + i * 2048);
        }

        // ---- S^T = mfma(K, Q): s[mq][kf], lane = S^T[key=kf*16+lg*4+r][q=l15]
        f32x4 s[2][8];
        #pragma unroll
        for (int mq = 0; mq < 2; ++mq)
            #pragma unroll
            for (int kf = 0; kf < 8; ++kf) s[mq][kf] = (f32x4){0.f, 0.f, 0.f, 0.f};
        #pragma unroll
        for (int kc = 0; kc < 2; ++kc) {
            #pragma unroll
            for (int kf = 0; kf < 8; ++kf) {
                int key = kf * 16 + l15;
                int ch = (kc * 4 + lg) ^ (key & 7);
                bf16x8 kfr = *(const bf16x8*)&KsC[key * 64 + (ch << 3)];
                s[0][kf] = __builtin_amdgcn_mfma_f32_16x16x32_bf16(kfr, qa[0][kc], s[0][kf], 0, 0, 0);
                s[1][kf] = __builtin_amdgcn_mfma_f32_16x16x32_bf16(kfr, qa[1][kc], s[1][kf], 0, 0, 0);
            }
        }

        // ---- per-mq online softmax (scores already exp2-domain) ----
        unsigned pk[2][8][2];
        #pragma unroll
        for (int mq = 0; mq < 2; ++mq) {
            float mx = -INFINITY;
            #pragma unroll
            for (int kf = 0; kf < 8; ++kf)
                mx = fmaxf(mx, fmaxf(fmaxf(s[mq][kf][0], s[mq][kf][1]),
                                     fmaxf(s[mq][kf][2], s[mq][kf][3])));
            mx = fmaxf(mx, __shfl_xor(mx, 16));
            mx = fmaxf(mx, __shfl_xor(mx, 32));

            if (!__all(mx <= m_run[mq] + 12.0f)) {     // defer-max
                float mnew = fmaxf(m_run[mq], mx);
                float alpha = exp2f(m_run[mq] - mnew);
                m_run[mq] = mnew;
                l_run[mq] *= alpha;
                #pragma unroll
                for (int r = 0; r < 4; ++r) {
                    float ar = __shfl(alpha, lg * 20 + r);
                    #pragma unroll
                    for (int nf = 0; nf < 4; ++nf) o[mq][nf][r] *= ar;
                }
            }

            float sum = 0.0f;
            #pragma unroll
            for (int kf = 0; kf < 8; ++kf) {
                float p0 = exp2f(s[mq][kf][0] - m_run[mq]);
                float p1 = exp2f(s[mq][kf][1] - m_run[mq]);
                float p2 = exp2f(s[mq][kf][2] - m_run[mq]);
                float p3 = exp2f(s[mq][kf][3] - m_run[mq]);
                sum += (p0 + p1) + (p2 + p3);
                pk[mq][kf][0] = cvt_pk_bf16(p0, p1);
                pk[mq][kf][1] = cvt_pk_bf16(p2, p3);
            }
            sum += __shfl_xor(sum, 16);
            sum += __shfl_xor(sum, 32);
            l_run[mq] += sum;
        }

        // ---- PV: redistribute P, share V fragments across both mq ----
        const int srcA = ((lg & 1) << 5) | l15;
        const int srcB = srcA + 16;
        const bool hi = (lg >= 2);
        #pragma unroll
        for (int kc = 0; kc < 4; ++kc) {
            union { unsigned u[4]; bf16x8 v; } pa[2];
            #pragma unroll
            for (int mq = 0; mq < 2; ++mq) {
                unsigned a0 = (unsigned)__shfl((int)pk[mq][2 * kc][0], srcA);
                unsigned a1 = (unsigned)__shfl((int)pk[mq][2 * kc][1], srcA);
                unsigned a2 = (unsigned)__shfl((int)pk[mq][2 * kc][0], srcB);
                unsigned a3 = (unsigned)__shfl((int)pk[mq][2 * kc][1], srcB);
                unsigned c0 = (unsigned)__shfl((int)pk[mq][2 * kc + 1][0], srcA);
                unsigned c1 = (unsigned)__shfl((int)pk[mq][2 * kc + 1][1], srcA);
                unsigned c2 = (unsigned)__shfl((int)pk[mq][2 * kc + 1][0], srcB);
                unsigned c3 = (unsigned)__shfl((int)pk[mq][2 * kc + 1][1], srcB);
                pa[mq].u[0] = hi ? c0 : a0;
                pa[mq].u[1] = hi ? c1 : a1;
                pa[mq].u[2] = hi ? c2 : a2;
                pa[mq].u[3] = hi ? c3 : a3;
            }
            #pragma unroll
            for (int nf = 0; nf < 4; ++nf) {
                int d = nf * 16 + l15;
                int ch = (kc * 4 + lg) ^ (d & 15);
                bf16x8 vb = *(const bf16x8*)&VtC[d * 128 + (ch << 3)];
                o[0][nf] = __builtin_amdgcn_mfma_f32_16x16x32_bf16(pa[0].v, vb, o[0][nf], 0, 0, 0);
                o[1][nf] = __builtin_amdgcn_mfma_f32_16x16x32_bf16(pa[1].v, vb, o[1][nf], 0, 0, 0);
            }
        }
        __syncthreads();   // buf^1 staged (vmcnt drain) + all waves done with cur
    }

    // ---- epilogue ----
    #pragma unroll
    for (int mq = 0; mq < 2; ++mq) {
        #pragma unroll
        for (int r = 0; r < 4; ++r) {
            float lr = __shfl(l_run[mq], lg * 20 + r);
            float inv = 1.0f / lr;
            int qrow = w * 32 + mq * 16 + lg * 4 + r;
            #pragma unroll
            for (int nf = 0; nf < 4; ++nf)
                attnb[(size_t)(row0 + qrow) * EMB + h * HD + nf * 16 + l15] =
                    f2bf(o[mq][nf][r] * inv);
        }
    }
}

// ---------------------------------------------------------------------------
extern "C" void kernel_launch(void* const* d_in, const int* in_sizes, int n_in,
                              void* d_out, int out_size, void* d_ws, size_t ws_size,
                              hipStream_t stream) {
    const float* x     = (const float*)d_in[0];
    const float* W_qkv = (const float*)d_in[1];
    const float* b_qkv = (const float*)d_in[2];
    const float* W_out = (const float*)d_in[3];
    const float* b_out = (const float*)d_in[4];
    float* out = (float*)d_out;

    // ws: xb 8M | wqkvb 6M | woutb 2M | qkvb 24M | attnb 8M | vtg 8M | bqs 12K
    char* ws = (char*)d_ws;
    unsigned short* xb     = (unsigned short*)(ws);
    unsigned short* wqkvb  = (unsigned short*)(ws + (8u << 20));
    unsigned short* woutb  = (unsigned short*)(ws + (14u << 20));
    unsigned short* qkvb   = (unsigned short*)(ws + (16u << 20));
    unsigned short* attnb  = (unsigned short*)(ws + (40u << 20));
    unsigned short* vtg    = (unsigned short*)(ws + (48u << 20));
    float*          bqs    = (float*)(ws + (56u << 20));

    const int M = BSZ * SEQ;            // 4096

    convert_all<<<(NTOT / 8 + 255) / 256, 256, 0, stream>>>(
        x, W_qkv, W_out, b_qkv, xb, wqkvb, woutb, bqs);

    gemm_bf16_nt<2><<<dim3(QKV3 / 128, M / 128), 256, 0, stream>>>(
        xb, wqkvb, bqs, qkvb, vtg, M, QKV3, DIN);

    attn_mfma<<<512, 256, 0, stream>>>(qkvb, vtg, attnb);

    gemm_bf16_nt<0><<<dim3(EMB / 128, M / 128), 256, 0, stream>>>(
        attnb, woutb, b_out, out, nullptr, M, EMB, DIN);
}

// Round 6
// 147.061 us; speedup vs baseline: 1.2180x; 1.0459x over previous
//
#include <hip/hip_runtime.h>
#include <hip/hip_bf16.h>

#define BSZ 2
#define SEQ 2048
#define DIN 1024
#define EMB 1024
#define NH  16
#define HD  64
#define QKV3 3072

typedef short bf16x8 __attribute__((ext_vector_type(8)));
typedef short bf16x4 __attribute__((ext_vector_type(4)));
typedef float f32x4  __attribute__((ext_vector_type(4)));
typedef unsigned int u32;

#define CSCL 0.18033688f   // 0.125 * log2(e)

__device__ __forceinline__ unsigned short f2bf(float f) {
    union { float f; unsigned int u; } v; v.f = f;
    unsigned int r = v.u + 0x7fffu + ((v.u >> 16) & 1u);   // RNE
    return (unsigned short)(r >> 16);
}

__device__ __forceinline__ unsigned cvt_pk_bf16(float lo, float hi) {
    unsigned r;
    asm("v_cvt_pk_bf16_f32 %0, %1, %2" : "=v"(r) : "v"(lo), "v"(hi));
    return r;
}

// async global -> LDS, 16 B per lane; lds base must be wave-uniform
__device__ __forceinline__ void gload16(const unsigned short* g, short* lds) {
    __builtin_amdgcn_global_load_lds(
        (const __attribute__((address_space(1))) u32*)g,
        (__attribute__((address_space(3))) u32*)lds, 16, 0, 0);
}

// ---------------------------------------------------------------------------
// Fused fp32->bf16 conversion: x | W_qkv (Q-rows pre-scaled) | W_out | b_qkv
// ---------------------------------------------------------------------------
#define NX  (BSZ * SEQ * DIN)     // 4194304
#define NWQ (QKV3 * DIN)          // 3145728
#define NWO (EMB * EMB)           // 1048576
#define NTOT (NX + NWQ + NWO + QKV3)

__global__ __launch_bounds__(256) void convert_all(
    const float* __restrict__ x, const float* __restrict__ Wq,
    const float* __restrict__ Wo, const float* __restrict__ bq,
    unsigned short* __restrict__ xb, unsigned short* __restrict__ wqb,
    unsigned short* __restrict__ wob, float* __restrict__ bqs)
{
    int i8 = (blockIdx.x * 256 + threadIdx.x) * 8;
    if (i8 >= NTOT) return;
    if (i8 < NX) {
        float4 a = *(const float4*)(x + i8);
        float4 b = *(const float4*)(x + i8 + 4);
        bf16x8 r;
        r[0] = (short)f2bf(a.x); r[1] = (short)f2bf(a.y);
        r[2] = (short)f2bf(a.z); r[3] = (short)f2bf(a.w);
        r[4] = (short)f2bf(b.x); r[5] = (short)f2bf(b.y);
        r[6] = (short)f2bf(b.z); r[7] = (short)f2bf(b.w);
        *(bf16x8*)(xb + i8) = r;
    } else if (i8 < NX + NWQ) {
        int i = i8 - NX;
        int row = i >> 10;
        float sc = ((row % 192) < 64) ? CSCL : 1.0f;
        float4 a = *(const float4*)(Wq + i);
        float4 b = *(const float4*)(Wq + i + 4);
        bf16x8 r;
        r[0] = (short)f2bf(a.x * sc); r[1] = (short)f2bf(a.y * sc);
        r[2] = (short)f2bf(a.z * sc); r[3] = (short)f2bf(a.w * sc);
        r[4] = (short)f2bf(b.x * sc); r[5] = (short)f2bf(b.y * sc);
        r[6] = (short)f2bf(b.z * sc); r[7] = (short)f2bf(b.w * sc);
        *(bf16x8*)(wqb + i) = r;
    } else if (i8 < NX + NWQ + NWO) {
        int i = i8 - NX - NWQ;
        float4 a = *(const float4*)(Wo + i);
        float4 b = *(const float4*)(Wo + i + 4);
        bf16x8 r;
        r[0] = (short)f2bf(a.x); r[1] = (short)f2bf(a.y);
        r[2] = (short)f2bf(a.z); r[3] = (short)f2bf(a.w);
        r[4] = (short)f2bf(b.x); r[5] = (short)f2bf(b.y);
        r[6] = (short)f2bf(b.z); r[7] = (short)f2bf(b.w);
        *(bf16x8*)(wob + i) = r;
    } else {
        int i = i8 - NX - NWQ - NWO;
        #pragma unroll
        for (int j = 0; j < 8; ++j) {
            float v = bq[i + j];
            if (((i + j) % 192) < 64) v *= CSCL;
            bqs[i + j] = v;
        }
    }
}

// ---------------------------------------------------------------------------
// bf16 MFMA GEMM (NT): C = A @ W^T + bias. 128x128 tile, BK=32, 4 waves.
// global_load_lds staging into linear [128][32] LDS (m97 structure).
// MODE 0: f32 out.  MODE 2: qkv epilogue — Q cols normal bf16, K cols
// chunk-swizzled bf16 (stored[row][c^(row&7)]), V cols written transposed +
// chunk-swizzled into vtg[b][h][d][s] (b64-packed), qkvb V-section skipped.
// ---------------------------------------------------------------------------
template <int MODE>
__global__ __launch_bounds__(256) void gemm_bf16_nt(
    const unsigned short* __restrict__ A, const unsigned short* __restrict__ W,
    const float* __restrict__ bias, void* __restrict__ Cout,
    unsigned short* __restrict__ Vout,
    int M, int N, int K)
{
    __shared__ short As[128 * 32];
    __shared__ short Bs[128 * 32];

    const int tid = threadIdx.x;
    const int m0 = blockIdx.y * 128, n0 = blockIdx.x * 128;
    const int w = tid >> 6, lane = tid & 63;
    const int lg = lane >> 4, l15 = lane & 15;
    const int wr = w >> 1, wc = w & 1;

    const int srow = w * 16 + (lane >> 2);
    const int scol = (lane & 3) * 8;
    const unsigned short* Ap = A + (size_t)(m0 + srow) * K + scol;
    const unsigned short* Wp = W + (size_t)(n0 + srow) * K + scol;
    short* AsW = As + w * 512;
    short* BsW = Bs + w * 512;

    f32x4 acc[4][4] = {};

    for (int k0 = 0; k0 < K; k0 += 32) {
        gload16(Ap + k0,                  AsW);
        gload16(Ap + k0 + (size_t)64 * K, AsW + 2048);
        gload16(Wp + k0,                  BsW);
        gload16(Wp + k0 + (size_t)64 * K, BsW + 2048);
        __syncthreads();

        bf16x8 af[4], bfr[4];
        #pragma unroll
        for (int mf = 0; mf < 4; ++mf)
            af[mf] = *(const bf16x8*)&As[(wr * 64 + mf * 16 + l15) * 32 + lg * 8];
        #pragma unroll
        for (int nf = 0; nf < 4; ++nf)
            bfr[nf] = *(const bf16x8*)&Bs[(wc * 64 + nf * 16 + l15) * 32 + lg * 8];
        #pragma unroll
        for (int mf = 0; mf < 4; ++mf)
            #pragma unroll
            for (int nf = 0; nf < 4; ++nf)
                acc[mf][nf] = __builtin_amdgcn_mfma_f32_16x16x32_bf16(
                    af[mf], bfr[nf], acc[mf][nf], 0, 0, 0);
        __syncthreads();
    }

    #pragma unroll
    for (int nf = 0; nf < 4; ++nf) {
        int colbase = n0 + wc * 64 + nf * 16;
        int col = colbase + l15;
        float bv = bias[col];
        int sect = (MODE == 2) ? ((colbase % 192) / 64) : 0;
        if (MODE == 2 && sect == 2) {
            // ---- V: write transposed + swizzled into vtg ----
            int h = colbase / 192;
            int dd = (colbase % 192) - 128 + l15;    // 0..63
            #pragma unroll
            for (int mf = 0; mf < 4; ++mf) {
                int row = m0 + wr * 64 + mf * 16 + lg * 4;   // r = 0
                int bz = row >> 11, sl = row & 2047;
                int cp = ((sl >> 3) & 15) ^ (dd & 15);
                int sdst = (sl & ~127) | (cp << 3) | (sl & 7);
                bf16x4 p;
                #pragma unroll
                for (int r = 0; r < 4; ++r)
                    p[r] = (short)f2bf(acc[mf][nf][r] + bv);
                *(bf16x4*)&Vout[((size_t)(bz * NH + h) * HD + dd) * SEQ + sdst] = p;
            }
        } else {
            bool isK = (MODE == 2) && (sect == 1);
            #pragma unroll
            for (int mf = 0; mf < 4; ++mf) {
                #pragma unroll
                for (int r = 0; r < 4; ++r) {
                    int row = m0 + wr * 64 + mf * 16 + lg * 4 + r;
                    float v = acc[mf][nf][r] + bv;
                    if (MODE == 0) {
                        ((float*)Cout)[(size_t)row * N + col] = v;
                    } else {
                        int scol2 = col;
                        if (isK) {
                            int cc = (col >> 3) & 7;
                            scol2 = col + (((cc ^ (row & 7)) - cc) << 3);
                        }
                        ((unsigned short*)Cout)[(size_t)row * N + scol2] = f2bf(v);
                    }
                }
            }
        }
    }
}

// ---------------------------------------------------------------------------
// MFMA flash attention: Q-tile 128 = 8 waves x 16 q-rows (512 thr), KVBLK=128,
// double-buffered K/V LDS with stage-ahead global_load_lds prefetch,
// swapped QK^T + in-register softmax (pre-scaled), defer-max, cvt_pk.
// grid 512 (XCD-swizzled), 2 blocks/CU x 8 waves = 4 waves/SIMD.
// ---------------------------------------------------------------------------
__global__ __launch_bounds__(512, 4) void attn_mfma(
    const unsigned short* __restrict__ qkvb,
    const unsigned short* __restrict__ vtg,
    unsigned short* __restrict__ attnb)
{
    __shared__ short Ks[2 * 128 * 64];   // [buf][key][c], pre-swizzled chunks
    __shared__ short VT[2 * 64 * 128];   // [buf][d][c],   pre-swizzled chunks

    const int tid = threadIdx.x;
    const int fl = blockIdx.x;
    const int swz = ((fl & 7) << 6) | (fl >> 3);   // bijective, 512 blocks
    const int qt = swz & 15, h = (swz >> 4) & 15, b = swz >> 8;

    const int w = tid >> 6, lane = tid & 63;
    const int lg = lane >> 4, l15 = lane & 15;

    const int row0 = b * SEQ + qt * 128;
    const int colq = h * 192, colk = colq + 64;

    // Q fragments: q-row = row0 + w*16 + l15, k = kc*32 + lg*8 + j (CSCL-scaled)
    bf16x8 qa[2];
    {
        const unsigned short* qp =
            qkvb + (size_t)(row0 + w * 16 + l15) * QKV3 + colq + lg * 8;
        qa[0] = *(const bf16x8*)qp;
        qa[1] = *(const bf16x8*)(qp + 32);
    }

    // staging bases (per-lane global, wave-uniform LDS). 512 thr:
    // K: issue i covers rows i*64 + w*8 + (lane>>3), col chunk (lane&7)*8
    // V: issue i covers d    i*32 + w*4 + (lane>>4), col chunk (lane&15)*8
    const unsigned short* kg = qkvb + (size_t)(b * SEQ + w * 8 + (lane >> 3)) * QKV3
                                    + colk + (lane & 7) * 8;
    const unsigned short* vg = vtg + ((size_t)(b * NH + h) * HD + w * 4 + (lane >> 4)) * SEQ
                                   + (lane & 15) * 8;

    float m_run = -INFINITY, l_run = 0.0f;
    f32x4 o[4] = {};

    const int NT = SEQ / 128;   // 16

    // prologue: stage tile 0 into buf 0
    {
        short* KsW = Ks + w * 512;
        short* VtW = VT + w * 512;
        #pragma unroll
        for (int i = 0; i < 2; ++i)
            gload16(kg + (size_t)(i * 64) * QKV3, KsW + i * 4096);
        #pragma unroll
        for (int i = 0; i < 2; ++i)
            gload16(vg + (size_t)(i * 32) * SEQ, VtW + i * 4096);
    }
    __syncthreads();

    for (int kt = 0; kt < NT; ++kt) {
        const int cur = kt & 1;
        short* KsC = Ks + cur * 8192;
        short* VtC = VT + cur * 8192;

        // ---- stage-ahead: issue next tile's loads into buf^1 ----
        if (kt < NT - 1) {
            short* KsW = Ks + (cur ^ 1) * 8192 + w * 512;
            short* VtW = VT + (cur ^ 1) * 8192 + w * 512;
            const unsigned short* kg0 = kg + (size_t)((kt + 1) * 128) * QKV3;
            const unsigned short* vg0 = vg + (kt + 1) * 128;
            #pragma unroll
            for (int i = 0; i < 2; ++i)
                gload16(kg0 + (size_t)(i * 64) * QKV3, KsW + i * 4096);
            #pragma unroll
            for (int i = 0; i < 2; ++i)
                gload16(vg0 + (size_t)(i * 32) * SEQ, VtW + i * 4096);
        }

        // ---- S^T = mfma(K, Q): lane holds S^T[key=kf*16+lg*4+r][q=l15] ----
        f32x4 s[8];
        #pragma unroll
        for (int kf = 0; kf < 8; ++kf) s[kf] = (f32x4){0.f, 0.f, 0.f, 0.f};
        #pragma unroll
        for (int kc = 0; kc < 2; ++kc) {
            #pragma unroll
            for (int kf = 0; kf < 8; ++kf) {
                int key = kf * 16 + l15;
                int ch = (kc * 4 + lg) ^ (key & 7);
                bf16x8 kfr = *(const bf16x8*)&KsC[key * 64 + (ch << 3)];
                s[kf] = __builtin_amdgcn_mfma_f32_16x16x32_bf16(kfr, qa[kc], s[kf], 0, 0, 0);
            }
        }

        // ---- in-register online softmax (scores already exp2-domain) ----
        float mx = -INFINITY;
        #pragma unroll
        for (int kf = 0; kf < 8; ++kf)
            mx = fmaxf(mx, fmaxf(fmaxf(s[kf][0], s[kf][1]),
                                 fmaxf(s[kf][2], s[kf][3])));
        mx = fmaxf(mx, __shfl_xor(mx, 16));
        mx = fmaxf(mx, __shfl_xor(mx, 32));

        if (!__all(mx <= m_run + 12.0f)) {     // defer-max (T13), wave-uniform
            float mnew = fmaxf(m_run, mx);
            float alpha = exp2f(m_run - mnew);
            m_run = mnew;
            l_run *= alpha;
            #pragma unroll
            for (int r = 0; r < 4; ++r) {
                float ar = __shfl(alpha, lg * 20 + r);
                #pragma unroll
                for (int nf = 0; nf < 4; ++nf) o[nf][r] *= ar;
            }
        }

        float sum = 0.0f;
        unsigned pk[8][2];
        #pragma unroll
        for (int kf = 0; kf < 8; ++kf) {
            float p0 = exp2f(s[kf][0] - m_run);
            float p1 = exp2f(s[kf][1] - m_run);
            float p2 = exp2f(s[kf][2] - m_run);
            float p3 = exp2f(s[kf][3] - m_run);
            sum += (p0 + p1) + (p2 + p3);
            pk[kf][0] = cvt_pk_bf16(p0, p1);
            pk[kf][1] = cvt_pk_bf16(p2, p3);
        }
        sum += __shfl_xor(sum, 16);
        sum += __shfl_xor(sum, 32);
        l_run += sum;

        // ---- PV: redistribute P to A-frag nominal (row=q=l15, k=key) ----
        const int srcA = ((lg & 1) << 5) | l15;
        const int srcB = srcA + 16;
        const bool hi = (lg >= 2);
        #pragma unroll
        for (int kc = 0; kc < 4; ++kc) {
            unsigned a0 = (unsigned)__shfl((int)pk[2 * kc][0], srcA);
            unsigned a1 = (unsigned)__shfl((int)pk[2 * kc][1], srcA);
            unsigned a2 = (unsigned)__shfl((int)pk[2 * kc][0], srcB);
            unsigned a3 = (unsigned)__shfl((int)pk[2 * kc][1], srcB);
            unsigned c0 = (unsigned)__shfl((int)pk[2 * kc + 1][0], srcA);
            unsigned c1 = (unsigned)__shfl((int)pk[2 * kc + 1][1], srcA);
            unsigned c2 = (unsigned)__shfl((int)pk[2 * kc + 1][0], srcB);
            unsigned c3 = (unsigned)__shfl((int)pk[2 * kc + 1][1], srcB);
            union { unsigned u[4]; bf16x8 v; } pa;
            pa.u[0] = hi ? c0 : a0;
            pa.u[1] = hi ? c1 : a1;
            pa.u[2] = hi ? c2 : a2;
            pa.u[3] = hi ? c3 : a3;
            #pragma unroll
            for (int nf = 0; nf < 4; ++nf) {
                int d = nf * 16 + l15;
                int ch = (kc * 4 + lg) ^ (d & 15);
                bf16x8 vb = *(const bf16x8*)&VtC[d * 128 + (ch << 3)];
                o[nf] = __builtin_amdgcn_mfma_f32_16x16x32_bf16(pa.v, vb, o[nf], 0, 0, 0);
            }
        }
        __syncthreads();   // buf^1 staged (vmcnt drain) + all waves done with cur
    }

    // ---- epilogue ----
    #pragma unroll
    for (int r = 0; r < 4; ++r) {
        float lr = __shfl(l_run, lg * 20 + r);
        float inv = 1.0f / lr;
        int qrow = w * 16 + lg * 4 + r;
        #pragma unroll
        for (int nf = 0; nf < 4; ++nf)
            attnb[(size_t)(row0 + qrow) * EMB + h * HD + nf * 16 + l15] =
                f2bf(o[nf][r] * inv);
    }
}

// ---------------------------------------------------------------------------
extern "C" void kernel_launch(void* const* d_in, const int* in_sizes, int n_in,
                              void* d_out, int out_size, void* d_ws, size_t ws_size,
                              hipStream_t stream) {
    const float* x     = (const float*)d_in[0];
    const float* W_qkv = (const float*)d_in[1];
    const float* b_qkv = (const float*)d_in[2];
    const float* W_out = (const float*)d_in[3];
    const float* b_out = (const float*)d_in[4];
    float* out = (float*)d_out;

    // ws: xb 8M | wqkvb 6M | woutb 2M | qkvb 24M | attnb 8M | vtg 8M | bqs 12K
    char* ws = (char*)d_ws;
    unsigned short* xb     = (unsigned short*)(ws);
    unsigned short* wqkvb  = (unsigned short*)(ws + (8u << 20));
    unsigned short* woutb  = (unsigned short*)(ws + (14u << 20));
    unsigned short* qkvb   = (unsigned short*)(ws + (16u << 20));
    unsigned short* attnb  = (unsigned short*)(ws + (40u << 20));
    unsigned short* vtg    = (unsigned short*)(ws + (48u << 20));
    float*          bqs    = (float*)(ws + (56u << 20));

    const int M = BSZ * SEQ;            // 4096

    convert_all<<<(NTOT / 8 + 255) / 256, 256, 0, stream>>>(
        x, W_qkv, W_out, b_qkv, xb, wqkvb, woutb, bqs);

    gemm_bf16_nt<2><<<dim3(QKV3 / 128, M / 128), 256, 0, stream>>>(
        xb, wqkvb, bqs, qkvb, vtg, M, QKV3, DIN);

    attn_mfma<<<512, 512, 0, stream>>>(qkvb, vtg, attnb);

    gemm_bf16_nt<0><<<dim3(EMB / 128, M / 128), 256, 0, stream>>>(
        attnb, woutb, b_out, out, nullptr, M, EMB, DIN);
}

// Round 7
// 139.526 us; speedup vs baseline: 1.2837x; 1.0540x over previous
//
#include <hip/hip_runtime.h>
#include <hip/hip_bf16.h>

#define BSZ 2
#define SEQ 2048
#define DIN 1024
#define EMB 1024
#define NH  16
#define HD  64
#define QKV3 3072

typedef short bf16x8 __attribute__((ext_vector_type(8)));
typedef short bf16x4 __attribute__((ext_vector_type(4)));
typedef float f32x4  __attribute__((ext_vector_type(4)));
typedef float f32x16 __attribute__((ext_vector_type(16)));
typedef unsigned int u32;

#define CSCL 0.18033688f   // 0.125 * log2(e)

__device__ __forceinline__ unsigned short f2bf(float f) {
    union { float f; unsigned int u; } v; v.f = f;
    unsigned int r = v.u + 0x7fffu + ((v.u >> 16) & 1u);   // RNE
    return (unsigned short)(r >> 16);
}

__device__ __forceinline__ unsigned cvt_pk_bf16(float lo, float hi) {
    unsigned r;
    asm("v_cvt_pk_bf16_f32 %0, %1, %2" : "=v"(r) : "v"(lo), "v"(hi));
    return r;
}

// async global -> LDS, 16 B per lane; lds base must be wave-uniform
__device__ __forceinline__ void gload16(const unsigned short* g, short* lds) {
    __builtin_amdgcn_global_load_lds(
        (const __attribute__((address_space(1))) u32*)g,
        (__attribute__((address_space(3))) u32*)lds, 16, 0, 0);
}

// ---------------------------------------------------------------------------
// Fused fp32->bf16 conversion: x | W_qkv (Q-rows pre-scaled) | W_out | b_qkv
// ---------------------------------------------------------------------------
#define NX  (BSZ * SEQ * DIN)     // 4194304
#define NWQ (QKV3 * DIN)          // 3145728
#define NWO (EMB * EMB)           // 1048576
#define NTOT (NX + NWQ + NWO + QKV3)

__global__ __launch_bounds__(256) void convert_all(
    const float* __restrict__ x, const float* __restrict__ Wq,
    const float* __restrict__ Wo, const float* __restrict__ bq,
    unsigned short* __restrict__ xb, unsigned short* __restrict__ wqb,
    unsigned short* __restrict__ wob, float* __restrict__ bqs)
{
    int i8 = (blockIdx.x * 256 + threadIdx.x) * 8;
    if (i8 >= NTOT) return;
    if (i8 < NX) {
        float4 a = *(const float4*)(x + i8);
        float4 b = *(const float4*)(x + i8 + 4);
        bf16x8 r;
        r[0] = (short)f2bf(a.x); r[1] = (short)f2bf(a.y);
        r[2] = (short)f2bf(a.z); r[3] = (short)f2bf(a.w);
        r[4] = (short)f2bf(b.x); r[5] = (short)f2bf(b.y);
        r[6] = (short)f2bf(b.z); r[7] = (short)f2bf(b.w);
        *(bf16x8*)(xb + i8) = r;
    } else if (i8 < NX + NWQ) {
        int i = i8 - NX;
        int row = i >> 10;
        float sc = ((row % 192) < 64) ? CSCL : 1.0f;
        float4 a = *(const float4*)(Wq + i);
        float4 b = *(const float4*)(Wq + i + 4);
        bf16x8 r;
        r[0] = (short)f2bf(a.x * sc); r[1] = (short)f2bf(a.y * sc);
        r[2] = (short)f2bf(a.z * sc); r[3] = (short)f2bf(a.w * sc);
        r[4] = (short)f2bf(b.x * sc); r[5] = (short)f2bf(b.y * sc);
        r[6] = (short)f2bf(b.z * sc); r[7] = (short)f2bf(b.w * sc);
        *(bf16x8*)(wqb + i) = r;
    } else if (i8 < NX + NWQ + NWO) {
        int i = i8 - NX - NWQ;
        float4 a = *(const float4*)(Wo + i);
        float4 b = *(const float4*)(Wo + i + 4);
        bf16x8 r;
        r[0] = (short)f2bf(a.x); r[1] = (short)f2bf(a.y);
        r[2] = (short)f2bf(a.z); r[3] = (short)f2bf(a.w);
        r[4] = (short)f2bf(b.x); r[5] = (short)f2bf(b.y);
        r[6] = (short)f2bf(b.z); r[7] = (short)f2bf(b.w);
        *(bf16x8*)(wob + i) = r;
    } else {
        int i = i8 - NX - NWQ - NWO;
        #pragma unroll
        for (int j = 0; j < 8; ++j) {
            float v = bq[i + j];
            if (((i + j) % 192) < 64) v *= CSCL;
            bqs[i + j] = v;
        }
    }
}

// ---------------------------------------------------------------------------
// bf16 MFMA GEMM (NT): C = A @ W^T + bias. 128x128 tile, BK=32, 4 waves.
// global_load_lds staging into linear [128][32] LDS (m97 structure).
// MODE 0: f32 out.  MODE 2: qkv epilogue — Q cols normal bf16, K cols
// chunk-swizzled bf16 (stored[row][c^(row&7)]); V cols written transposed
// into vtg[b][h][d][tile*128 + perm(key)] matching the attn PV k-mapping:
// within a 128-key tile, chunk = ((kb*2+c)*2+hi) ^ (d&15), element
// j = (rem2&3)+4*(rem2>>3) where key = kb*32+c*16+hi*4+... (see attn).
// ---------------------------------------------------------------------------
template <int MODE>
__global__ __launch_bounds__(256) void gemm_bf16_nt(
    const unsigned short* __restrict__ A, const unsigned short* __restrict__ W,
    const float* __restrict__ bias, void* __restrict__ Cout,
    unsigned short* __restrict__ Vout,
    int M, int N, int K)
{
    __shared__ short As[128 * 32];
    __shared__ short Bs[128 * 32];

    const int tid = threadIdx.x;
    const int m0 = blockIdx.y * 128, n0 = blockIdx.x * 128;
    const int w = tid >> 6, lane = tid & 63;
    const int lg = lane >> 4, l15 = lane & 15;
    const int wr = w >> 1, wc = w & 1;

    const int srow = w * 16 + (lane >> 2);
    const int scol = (lane & 3) * 8;
    const unsigned short* Ap = A + (size_t)(m0 + srow) * K + scol;
    const unsigned short* Wp = W + (size_t)(n0 + srow) * K + scol;
    short* AsW = As + w * 512;
    short* BsW = Bs + w * 512;

    f32x4 acc[4][4] = {};

    for (int k0 = 0; k0 < K; k0 += 32) {
        gload16(Ap + k0,                  AsW);
        gload16(Ap + k0 + (size_t)64 * K, AsW + 2048);
        gload16(Wp + k0,                  BsW);
        gload16(Wp + k0 + (size_t)64 * K, BsW + 2048);
        __syncthreads();

        bf16x8 af[4], bfr[4];
        #pragma unroll
        for (int mf = 0; mf < 4; ++mf)
            af[mf] = *(const bf16x8*)&As[(wr * 64 + mf * 16 + l15) * 32 + lg * 8];
        #pragma unroll
        for (int nf = 0; nf < 4; ++nf)
            bfr[nf] = *(const bf16x8*)&Bs[(wc * 64 + nf * 16 + l15) * 32 + lg * 8];
        #pragma unroll
        for (int mf = 0; mf < 4; ++mf)
            #pragma unroll
            for (int nf = 0; nf < 4; ++nf)
                acc[mf][nf] = __builtin_amdgcn_mfma_f32_16x16x32_bf16(
                    af[mf], bfr[nf], acc[mf][nf], 0, 0, 0);
        __syncthreads();
    }

    #pragma unroll
    for (int nf = 0; nf < 4; ++nf) {
        int colbase = n0 + wc * 64 + nf * 16;
        int col = colbase + l15;
        float bv = bias[col];
        int sect = (MODE == 2) ? ((colbase % 192) / 64) : 0;
        if (MODE == 2 && sect == 2) {
            // ---- V: write into vtg with the attn PV k-permutation ----
            int h = colbase / 192;
            int dd = (colbase % 192) - 128 + l15;    // 0..63
            #pragma unroll
            for (int mf = 0; mf < 4; ++mf) {
                int row = m0 + wr * 64 + mf * 16 + lg * 4;   // rows row..row+3
                int bz = row >> 11, sl = row & 2047;
                int T = sl >> 7;
                int chunk = ((((sl >> 5) & 3) * 2 + ((sl >> 4) & 1)) << 1) | (lg & 1);
                int ci = chunk ^ (dd & 15);
                int j0 = (lg >> 1) * 4;
                bf16x4 p;
                #pragma unroll
                for (int r = 0; r < 4; ++r)
                    p[r] = (short)f2bf(acc[mf][nf][r] + bv);
                *(bf16x4*)&Vout[((size_t)(bz * NH + h) * HD + dd) * SEQ
                                + T * 128 + ci * 8 + j0] = p;
            }
        } else {
            bool isK = (MODE == 2) && (sect == 1);
            #pragma unroll
            for (int mf = 0; mf < 4; ++mf) {
                #pragma unroll
                for (int r = 0; r < 4; ++r) {
                    int row = m0 + wr * 64 + mf * 16 + lg * 4 + r;
                    float v = acc[mf][nf][r] + bv;
                    if (MODE == 0) {
                        ((float*)Cout)[(size_t)row * N + col] = v;
                    } else {
                        int scol2 = col;
                        if (isK) {
                            int cc = (col >> 3) & 7;
                            scol2 = col + (((cc ^ (row & 7)) - cc) << 3);
                        }
                        ((unsigned short*)Cout)[(size_t)row * N + scol2] = f2bf(v);
                    }
                }
            }
        }
    }
}

// ---------------------------------------------------------------------------
// MFMA flash attention on 32x32x16: 4 waves x 32 q-rows (256 thr), KVBLK=128,
// dbuf K/V LDS + stage-ahead gload_lds. mfma(K,Q) -> S^T with q = lane&31:
// softmax fully lane-local. PV k-mapping chosen so the P A-fragment is regs
// 8c..8c+7 verbatim (no shuffles); V pre-permuted in gemm1 epilogue to match.
// C/D layout (verified): col=lane&31, row=(reg&3)+8*(reg>>2)+4*(lane>>5).
// ---------------------------------------------------------------------------
__global__ __launch_bounds__(256, 2) void attn_mfma(
    const unsigned short* __restrict__ qkvb,
    const unsigned short* __restrict__ vtg,
    unsigned short* __restrict__ attnb)
{
    __shared__ short Ks[2 * 128 * 64];   // [buf][key][64d], chunk^(key&7) swz
    __shared__ short VT[2 * 64 * 128];   // [buf][d][128k], chunk^(d&15) swz

    const int tid = threadIdx.x;
    const int fl = blockIdx.x;
    const int swz = ((fl & 7) << 6) | (fl >> 3);   // bijective, 512 blocks
    const int qt = swz & 15, h = (swz >> 4) & 15, b = swz >> 8;

    const int w = tid >> 6, lane = tid & 63;
    const int l31 = lane & 31, hi = lane >> 5;

    const int row0 = b * SEQ + qt * 128;
    const int colq = h * 192, colk = colq + 64;

    // Q frags: row q = w*32 + l31, d = kc*16 + hi*8 + j (CSCL pre-scaled)
    bf16x8 qa[4];
    {
        const unsigned short* qp =
            qkvb + (size_t)(row0 + w * 32 + l31) * QKV3 + colq + hi * 8;
        qa[0] = *(const bf16x8*)qp;
        qa[1] = *(const bf16x8*)(qp + 16);
        qa[2] = *(const bf16x8*)(qp + 32);
        qa[3] = *(const bf16x8*)(qp + 48);
    }

    // staging bases (per-lane global, wave-uniform LDS)
    const unsigned short* kg = qkvb + (size_t)(b * SEQ + w * 8 + (lane >> 3)) * QKV3
                                    + colk + (lane & 7) * 8;
    const unsigned short* vg = vtg + ((size_t)(b * NH + h) * HD + w * 4 + (lane >> 4)) * SEQ
                                   + (lane & 15) * 8;

    // hoisted lane-constant LDS read offsets (shorts)
    int koff[4], voff[8];
    #pragma unroll
    for (int kc = 0; kc < 4; ++kc)
        koff[kc] = l31 * 64 + ((((kc << 1) | hi) ^ (l31 & 7)) << 3);
    #pragma unroll
    for (int j = 0; j < 8; ++j)
        voff[j] = l31 * 128 + ((((j << 1) | hi) ^ (l31 & 15)) << 3);

    float m_run = -INFINITY, l_run = 0.0f;
    f32x16 o0 = {}, o1 = {};     // o0: d = l31, o1: d = 32 + l31; q on regs

    const int NT = SEQ / 128;    // 16

    // prologue: stage tile 0 into buf 0
    {
        short* KsW = Ks + w * 512;
        short* VtW = VT + w * 512;
        #pragma unroll
        for (int i = 0; i < 4; ++i)
            gload16(kg + (size_t)(i * 32) * QKV3, KsW + i * 2048);
        #pragma unroll
        for (int i = 0; i < 4; ++i)
            gload16(vg + (size_t)(i * 16) * SEQ, VtW + i * 2048);
    }
    __syncthreads();

    for (int kt = 0; kt < NT; ++kt) {
        const int cur = kt & 1;
        const short* KsC = Ks + cur * 8192;
        const short* VtC = VT + cur * 8192;

        // ---- stage-ahead next tile into buf^1 ----
        if (kt < NT - 1) {
            short* KsW = Ks + (cur ^ 1) * 8192 + w * 512;
            short* VtW = VT + (cur ^ 1) * 8192 + w * 512;
            const unsigned short* kg0 = kg + (size_t)((kt + 1) * 128) * QKV3;
            const unsigned short* vg0 = vg + (kt + 1) * 128;
            #pragma unroll
            for (int i = 0; i < 4; ++i)
                gload16(kg0 + (size_t)(i * 32) * QKV3, KsW + i * 2048);
            #pragma unroll
            for (int i = 0; i < 4; ++i)
                gload16(vg0 + (size_t)(i * 16) * SEQ, VtW + i * 2048);
        }

        // ---- S^T = mfma(K, Q): col q = l31, key = (reg&3)+8*(reg>>2)+4hi+32kb
        f32x16 s0 = {}, s1 = {}, s2 = {}, s3 = {};
        __builtin_amdgcn_s_setprio(1);
        #pragma unroll
        for (int kc = 0; kc < 4; ++kc) {
            bf16x8 k0 = *(const bf16x8*)&KsC[koff[kc]];
            bf16x8 k1 = *(const bf16x8*)&KsC[koff[kc] + 2048];
            bf16x8 k2 = *(const bf16x8*)&KsC[koff[kc] + 4096];
            bf16x8 k3 = *(const bf16x8*)&KsC[koff[kc] + 6144];
            s0 = __builtin_amdgcn_mfma_f32_32x32x16_bf16(k0, qa[kc], s0, 0, 0, 0);
            s1 = __builtin_amdgcn_mfma_f32_32x32x16_bf16(k1, qa[kc], s1, 0, 0, 0);
            s2 = __builtin_amdgcn_mfma_f32_32x32x16_bf16(k2, qa[kc], s2, 0, 0, 0);
            s3 = __builtin_amdgcn_mfma_f32_32x32x16_bf16(k3, qa[kc], s3, 0, 0, 0);
        }
        __builtin_amdgcn_s_setprio(0);

        // ---- lane-local max over 64 regs + cross-half swap ----
        f32x16 mm;
        #pragma unroll
        for (int r = 0; r < 16; ++r)
            mm[r] = fmaxf(fmaxf(s0[r], s1[r]), fmaxf(s2[r], s3[r]));
        float mx = mm[0];
        #pragma unroll
        for (int r = 1; r < 16; ++r) mx = fmaxf(mx, mm[r]);
        mx = fmaxf(mx, __shfl_xor(mx, 32));

        if (!__all(mx <= m_run + 12.0f)) {     // defer-max (T13), wave-uniform
            float mnew = fmaxf(m_run, mx);
            float alpha = exp2f(m_run - mnew);
            m_run = mnew;
            l_run *= alpha;
            #pragma unroll
            for (int r = 0; r < 16; ++r) {
                int qloc = (r & 3) + 8 * (r >> 2) + 4 * hi;
                float aq = __shfl(alpha, qloc);
                o0[r] *= aq; o1[r] *= aq;
            }
        }

        // ---- per-kb: exp -> sum -> cvt_pk -> PV (A-frag = regs verbatim) ----
        f32x16 psum = {};
        auto kb_block = [&](f32x16& ss, int kb) {
            #pragma unroll
            for (int r = 0; r < 16; ++r) ss[r] = exp2f(ss[r] - m_run);
            #pragma unroll
            for (int r = 0; r < 16; ++r) psum[r] += ss[r];
            u32 wv[8];
            #pragma unroll
            for (int i = 0; i < 8; ++i)
                wv[i] = cvt_pk_bf16(ss[2 * i], ss[2 * i + 1]);
            #pragma unroll
            for (int c = 0; c < 2; ++c) {
                union { u32 u[4]; bf16x8 v; } pa;
                pa.u[0] = wv[4 * c + 0]; pa.u[1] = wv[4 * c + 1];
                pa.u[2] = wv[4 * c + 2]; pa.u[3] = wv[4 * c + 3];
                int j = kb * 2 + c;
                bf16x8 v0 = *(const bf16x8*)&VtC[voff[j]];
                bf16x8 v1 = *(const bf16x8*)&VtC[voff[j] + 4096];
                o0 = __builtin_amdgcn_mfma_f32_32x32x16_bf16(pa.v, v0, o0, 0, 0, 0);
                o1 = __builtin_amdgcn_mfma_f32_32x32x16_bf16(pa.v, v1, o1, 0, 0, 0);
            }
        };
        kb_block(s0, 0);
        kb_block(s1, 1);
        kb_block(s2, 2);
        kb_block(s3, 3);

        float sum = psum[0];
        #pragma unroll
        for (int r = 1; r < 16; ++r) sum += psum[r];
        sum += __shfl_xor(sum, 32);
        l_run += sum;

        __syncthreads();   // buf^1 staged (vmcnt drain) + all waves done w/ cur
    }

    // ---- epilogue: O[q on regs][d = db*32 + l31] / l(q) ----
    #pragma unroll
    for (int r = 0; r < 16; ++r) {
        int qloc = (r & 3) + 8 * (r >> 2) + 4 * hi;
        float lr = __shfl(l_run, qloc);
        float inv = 1.0f / lr;
        size_t grow = (size_t)(row0 + w * 32 + qloc) * EMB + h * HD;
        attnb[grow + l31]      = f2bf(o0[r] * inv);
        attnb[grow + 32 + l31] = f2bf(o1[r] * inv);
    }
}

// ---------------------------------------------------------------------------
extern "C" void kernel_launch(void* const* d_in, const int* in_sizes, int n_in,
                              void* d_out, int out_size, void* d_ws, size_t ws_size,
                              hipStream_t stream) {
    const float* x     = (const float*)d_in[0];
    const float* W_qkv = (const float*)d_in[1];
    const float* b_qkv = (const float*)d_in[2];
    const float* W_out = (const float*)d_in[3];
    const float* b_out = (const float*)d_in[4];
    float* out = (float*)d_out;

    // ws: xb 8M | wqkvb 6M | woutb 2M | qkvb 24M | attnb 8M | vtg 8M | bqs 12K
    char* ws = (char*)d_ws;
    unsigned short* xb     = (unsigned short*)(ws);
    unsigned short* wqkvb  = (unsigned short*)(ws + (8u << 20));
    unsigned short* woutb  = (unsigned short*)(ws + (14u << 20));
    unsigned short* qkvb   = (unsigned short*)(ws + (16u << 20));
    unsigned short* attnb  = (unsigned short*)(ws + (40u << 20));
    unsigned short* vtg    = (unsigned short*)(ws + (48u << 20));
    float*          bqs    = (float*)(ws + (56u << 20));

    const int M = BSZ * SEQ;            // 4096

    convert_all<<<(NTOT / 8 + 255) / 256, 256, 0, stream>>>(
        x, W_qkv, W_out, b_qkv, xb, wqkvb, woutb, bqs);

    gemm_bf16_nt<2><<<dim3(QKV3 / 128, M / 128), 256, 0, stream>>>(
        xb, wqkvb, bqs, qkvb, vtg, M, QKV3, DIN);

    attn_mfma<<<512, 256, 0, stream>>>(qkvb, vtg, attnb);

    gemm_bf16_nt<0><<<dim3(EMB / 128, M / 128), 256, 0, stream>>>(
        attnb, woutb, b_out, out, nullptr, M, EMB, DIN);
}